// Round 7
// baseline (200.809 us; speedup 1.0000x reference)
//
#include <hip/hip_runtime.h>
#include <stdint.h>

typedef unsigned short u16;
typedef __bf16 bf16x8 __attribute__((ext_vector_type(8)));
typedef float f32x4 __attribute__((ext_vector_type(4)));

__device__ __forceinline__ float b2f(u16 u) {
  union { uint32_t i; float f; } x; x.i = ((uint32_t)u) << 16; return x.f;
}
__device__ __forceinline__ u16 f2b(float f) {
  union { float f; uint32_t i; } x; x.f = f;
  uint32_t r = x.i + 0x7fffu + ((x.i >> 16) & 1u);
  return (u16)(r >> 16);
}
__device__ __forceinline__ uint4 pk8(const float4 a, const float4 b) {
  uint4 r;
  r.x = (uint32_t)f2b(a.x) | ((uint32_t)f2b(a.y) << 16);
  r.y = (uint32_t)f2b(a.z) | ((uint32_t)f2b(a.w) << 16);
  r.z = (uint32_t)f2b(b.x) | ((uint32_t)f2b(b.y) << 16);
  r.w = (uint32_t)f2b(b.z) | ((uint32_t)f2b(b.w) << 16);
  return r;
}
// async global->LDS, 16B per lane, LDS dest = wave-uniform base + lane*16
__device__ __forceinline__ void gload_lds16(const u16* g, u16* l) {
  __builtin_amdgcn_global_load_lds(
      (const __attribute__((address_space(1))) void*)g,
      (__attribute__((address_space(3))) void*)l, 16, 0, 0);
}

// ---------------------------------------------------------------------------
// prep: fp32->bf16 cvt of x|qkv_w|proj_w with 4-slot GEMM-operand swizzle:
// 16B chunk c (of 4) within each 32-col group of row r -> slot c^(r&3).
// blocks 0..4095: cvt (8 elems/thread). blocks 4096..4223: RoPE table
// tab[pos*32+idx] = {cos,sin}(pos * 10000^-(idx/32)).
// ---------------------------------------------------------------------------
__launch_bounds__(256)
__global__ void prep(const float* __restrict__ x, const float* __restrict__ wq,
                     const float* __restrict__ wp, u16* __restrict__ dst,
                     float* __restrict__ tab) {
  if (blockIdx.x >= 4096) {
    const int tid = (blockIdx.x - 4096) * 256 + threadIdx.x;  // 32768
    const int pos = tid >> 5, idx = tid & 31;
    const float f = pos * exp2f(idx * -0.41524101186092029f); // -log2(1e4)/32
    float s, c;
    sincosf(f, &s, &c);
    *(float2*)(tab + tid * 2) = make_float2(c, s);
    return;
  }
  const int i = (blockIdx.x * 256 + threadIdx.x) * 8;
  const float* src; int local, base;
  if (i < 4194304)      { src = x;  local = i;           base = 0; }
  else if (i < 7340032) { src = wq; local = i - 4194304; base = 4194304; }
  else                  { src = wp; local = i - 7340032; base = 7340032; }
  const int row = local >> 10, col = local & 1023;
  const int slot = ((col >> 3) & 3) ^ (row & 3);
  const float4 a = *(const float4*)(src + local);
  const float4 b = *(const float4*)(src + local + 4);
  *(uint4*)(dst + base + (row << 10) + (col & ~31) + (slot << 3)) = pk8(a, b);
}

// ---------------------------------------------------------------------------
// QKV GEMM + fused LN/RoPE/transpose epilogues.
// C[m,n] = sum_k A[m,k]*B[n,k]; operands 4-slot chunk-swizzled in global.
// 128x128 tile, BK=32 (16KB LDS), 4 waves (2x2 of 64x64), linear
// global_load_lds staging, swizzled conflict-free ds_read_b128 frag reads.
// Epilogue by n-region: q/k -> LayerNorm(D=64)+RoPE in fp32 (4 j-regs hold one
// head; partner d^32 = reg j^2), q linear scatter / k chunk-permuted scatter
// into [B,H,N,D]; v -> transposed-chunked [bh][nb][d][64], slot (jl>>3)^(d&7).
// ---------------------------------------------------------------------------
__launch_bounds__(256)
__global__ void gemm_qkv(const u16* __restrict__ A, const u16* __restrict__ Bw,
                         u16* __restrict__ Cp, u16* __restrict__ vt,
                         const float* __restrict__ qn_w, const float* __restrict__ qn_b,
                         const float* __restrict__ kn_w, const float* __restrict__ kn_b,
                         const float* __restrict__ tab, int K) {
  __shared__ __align__(16) u16 As[128 * 32];
  __shared__ __align__(16) u16 Bs[128 * 32];
  const int t = threadIdx.x;
  const int w = t >> 6, l = t & 63, lr = l & 15, lg = l >> 4;
  const int m0 = blockIdx.y * 128, n0 = blockIdx.x * 128;
  const int wm = (w >> 1) * 64, wn = (w & 1) * 64;
  const int srow = w * 32 + (l >> 2);
  const int scol = (l & 3) * 8;
  const u16* ga0 = A  + (m0 + srow) * K + scol;
  const u16* ga1 = ga0 + 16 * K;
  const u16* gb0 = Bw + (n0 + srow) * K + scol;
  const u16* gb1 = gb0 + 16 * K;
  u16* la0 = As + w * 1024;
  u16* la1 = As + w * 1024 + 512;
  u16* lb0 = Bs + w * 1024;
  u16* lb1 = Bs + w * 1024 + 512;

  f32x4 acc[4][4] = {};
  const int nk = K >> 5;
  for (int kt = 0; kt < nk; ++kt) {
    const int ko = kt * 32;
    __syncthreads();
    gload_lds16(ga0 + ko, la0);
    gload_lds16(ga1 + ko, la1);
    gload_lds16(gb0 + ko, lb0);
    gload_lds16(gb1 + ko, lb1);
    __syncthreads();
    bf16x8 af[4], bfr[4];
#pragma unroll
    for (int i = 0; i < 4; ++i) {
      const int ra = wm + i * 16 + lr;
      af[i] = *(const bf16x8*)(As + ra * 32 + ((lg ^ (ra & 3)) << 3));
    }
#pragma unroll
    for (int j = 0; j < 4; ++j) {
      const int rb = wn + j * 16 + lr;
      bfr[j] = *(const bf16x8*)(Bs + rb * 32 + ((lg ^ (rb & 3)) << 3));
    }
#pragma unroll
    for (int i = 0; i < 4; ++i)
#pragma unroll
      for (int j = 0; j < 4; ++j)
        acc[i][j] = __builtin_amdgcn_mfma_f32_16x16x32_bf16(af[i], bfr[j], acc[i][j], 0, 0, 0);
  }
  // epilogue. C/D layout: col=lane&15, row=(lane>>4)*4+reg
  const int whichB = blockIdx.x >> 3;              // 0=q 1=k 2=v
  const int hh = ((n0 + wn) >> 6) & 15;            // head (wave-uniform)
  if (whichB == 2) {
    // v: fused transpose into chunked [bh][nb][d][64], slot (jl>>3)^(d&7)
#pragma unroll
    for (int i = 0; i < 4; ++i)
#pragma unroll
      for (int j = 0; j < 4; ++j)
#pragma unroll
        for (int r = 0; r < 4; ++r) {
          const int gm = m0 + wm + i * 16 + lg * 4 + r;
          const int bh = (gm >> 10) * 16 + hh;
          const int pos = gm & 1023, nb = pos >> 6, jl = pos & 63;
          const int d = j * 16 + lr;
          vt[bh * 65536 + nb * 4096 + d * 64 + (((jl >> 3) ^ (d & 7)) << 3) + (jl & 7)] =
              f2b(acc[i][j][r]);
        }
    return;
  }
  // q/k: LayerNorm over D=64 (4 j-regs x 16 lanes) + RoPE (partner = j^2)
  const float* wl = whichB ? kn_w : qn_w;
  const float* bl = whichB ? kn_b : qn_b;
  float wln[4], bln[4];
#pragma unroll
  for (int j = 0; j < 4; ++j) { wln[j] = wl[j * 16 + lr]; bln[j] = bl[j * 16 + lr]; }
  u16* Cb = Cp + whichB * 4194304;
#pragma unroll
  for (int i = 0; i < 4; ++i)
#pragma unroll
    for (int r = 0; r < 4; ++r) {
      const int gm = m0 + wm + i * 16 + lg * 4 + r;
      const int pos = gm & 1023;
      float v0 = acc[i][0][r], v1 = acc[i][1][r], v2 = acc[i][2][r], v3 = acc[i][3][r];
      float s = v0 + v1 + v2 + v3;
#pragma unroll
      for (int m = 1; m < 16; m <<= 1) s += __shfl_xor(s, m);
      const float mu = s * 0.015625f;
      const float d0 = v0 - mu, d1 = v1 - mu, d2 = v2 - mu, d3 = v3 - mu;
      float qv = d0 * d0 + d1 * d1 + d2 * d2 + d3 * d3;
#pragma unroll
      for (int m = 1; m < 16; m <<= 1) qv += __shfl_xor(qv, m);
      const float rstd = rsqrtf(qv * 0.015625f + 1e-5f);
      float nn[4];
      nn[0] = d0 * rstd * wln[0] + bln[0];
      nn[1] = d1 * rstd * wln[1] + bln[1];
      nn[2] = d2 * rstd * wln[2] + bln[2];
      nn[3] = d3 * rstd * wln[3] + bln[3];
      const float2 csA = *(const float2*)(tab + (pos * 32 + lr) * 2);
      const float2 csB = *(const float2*)(tab + (pos * 32 + 16 + lr) * 2);
      float o[4];
      o[0] = nn[0] * csA.x - nn[2] * csA.y;
      o[1] = nn[1] * csB.x - nn[3] * csB.y;
      o[2] = nn[2] * csA.x + nn[0] * csA.y;
      o[3] = nn[3] * csB.x + nn[1] * csB.y;
      u16* cb = Cb + (((gm >> 10) * 16 + hh) << 16) + (pos << 6);
      if (whichB == 1) {
        const int key = pos & 7;
#pragma unroll
        for (int j = 0; j < 4; ++j) {
          const int d = j * 16 + lr;
          cb[((d >> 3) ^ key) * 8 + (d & 7)] = f2b(o[j]);
        }
      } else {
#pragma unroll
        for (int j = 0; j < 4; ++j) cb[j * 16 + lr] = f2b(o[j]);
      }
    }
}

// ---------------------------------------------------------------------------
// Projection GEMM: out[m,n] = sum_k ao[m,k]*wp[n,k] + bias[n], fp32 out.
// 128x64 tile (12KB LDS) -> 512 blocks = 2 blocks/CU (vs 1 at 128x128):
// doubles resident waves/SIMD to hide the barrier drains of the K-loop.
// 4 waves as 2x2 over (64m, 32n): acc[4][2] per wave.
// ---------------------------------------------------------------------------
__launch_bounds__(256)
__global__ void gemm_proj(const u16* __restrict__ A, const u16* __restrict__ Bw,
                          float* __restrict__ out, const float* __restrict__ bias,
                          int K) {
  __shared__ __align__(16) u16 As[128 * 32];
  __shared__ __align__(16) u16 Bs[64 * 32];
  const int t = threadIdx.x;
  const int w = t >> 6, l = t & 63, lr = l & 15, lg = l >> 4;
  const int m0 = blockIdx.y * 128, n0 = blockIdx.x * 64;
  const int wm = (w >> 1) * 64, wn = (w & 1) * 32;
  const int srowA = w * 32 + (l >> 2);
  const int srowB = w * 16 + (l >> 2);
  const int scol = (l & 3) * 8;
  const u16* ga0 = A  + (m0 + srowA) * K + scol;
  const u16* ga1 = ga0 + 16 * K;
  const u16* gb  = Bw + (n0 + srowB) * K + scol;
  u16* la0 = As + w * 1024;
  u16* la1 = As + w * 1024 + 512;
  u16* lb  = Bs + w * 512;

  f32x4 acc[4][2] = {};
  const int nk = K >> 5;
  for (int kt = 0; kt < nk; ++kt) {
    const int ko = kt * 32;
    __syncthreads();
    gload_lds16(ga0 + ko, la0);
    gload_lds16(ga1 + ko, la1);
    gload_lds16(gb + ko, lb);
    __syncthreads();
    bf16x8 af[4], bfr[2];
#pragma unroll
    for (int i = 0; i < 4; ++i) {
      const int ra = wm + i * 16 + lr;
      af[i] = *(const bf16x8*)(As + ra * 32 + ((lg ^ (ra & 3)) << 3));
    }
#pragma unroll
    for (int j = 0; j < 2; ++j) {
      const int rb = wn + j * 16 + lr;
      bfr[j] = *(const bf16x8*)(Bs + rb * 32 + ((lg ^ (rb & 3)) << 3));
    }
#pragma unroll
    for (int i = 0; i < 4; ++i)
#pragma unroll
      for (int j = 0; j < 2; ++j)
        acc[i][j] = __builtin_amdgcn_mfma_f32_16x16x32_bf16(af[i], bfr[j], acc[i][j], 0, 0, 0);
  }
#pragma unroll
  for (int i = 0; i < 4; ++i)
#pragma unroll
    for (int j = 0; j < 2; ++j)
#pragma unroll
      for (int r = 0; r < 4; ++r) {
        const int gm = m0 + wm + i * 16 + lg * 4 + r;
        const int gn = n0 + wn + j * 16 + lr;
        out[(gm << 10) + gn] = acc[i][j][r] + bias[gn];
      }
}

// ---------------------------------------------------------------------------
// Sliding-window attention with sinks (LDS-staged K/V via async burst,
// swizzled sources, P-buffer aliases Ks). ao store is 4-slot chunk-swizzled
// so ao is a valid swizzled GEMM operand for the proj GEMM.
// ---------------------------------------------------------------------------
__launch_bounds__(256, 2)
__global__ void attn_kernel(const u16* __restrict__ q, const u16* __restrict__ k,
                            const u16* __restrict__ vt, const float* __restrict__ sinks,
                            u16* __restrict__ ao) {
  __shared__ __align__(16) u16 Ks[20480];   // 320 rows x 64
  __shared__ __align__(16) u16 Vs[20480];   // 5 chunks x [64][64]
  const int t = threadIdx.x, w = t >> 6, l = t & 63, lr = l & 15, lg = l >> 4;
  const int bid = blockIdx.x;
  const int qb = bid & 15, h = (bid >> 4) & 15, b = bid >> 8;
  const int i0 = qb * 64 + w * 16;
  const int bh = b * 16 + h;
  const u16* qp = q + bh * 65536;
  const u16* kp = k + bh * 65536;
  const u16* vp = vt + bh * 65536;
  const int j0 = qb * 64 - 256;

#pragma unroll
  for (int i = 0; i < 10; ++i) {
    const int c = w * 10 + i;
    int off = j0 * 64 + c * 512 + l * 8;
    off = off < 0 ? 0 : off;
    gload_lds16(kp + off, Ks + c * 512);
  }
#pragma unroll
  for (int i = 0; i < 10; ++i) {
    const int c = w * 10 + i;
    const int n = c >> 3, p = c & 7;
    int nb = qb - 4 + n;
    nb = nb < 0 ? 0 : nb;
    gload_lds16(vp + nb * 4096 + p * 512 + l * 8, Vs + c * 512);
  }
  const bf16x8 qf0 = *(const bf16x8*)(qp + (i0 + lr) * 64 + lg * 8);
  const bf16x8 qf1 = *(const bf16x8*)(qp + (i0 + lr) * 64 + 32 + lg * 8);
  __syncthreads();

  const int key = lr & 7;
  f32x4 sacc[17];
#pragma unroll
  for (int jt = 0; jt < 17; ++jt) {
    const int r = w * 16 + jt * 16 + lr;
    const bf16x8 kf0 = *(const bf16x8*)(Ks + r * 64 + ((lg ^ key)) * 8);
    const bf16x8 kf1 = *(const bf16x8*)(Ks + r * 64 + (((lg + 4) ^ key)) * 8);
    f32x4 a = {0.f, 0.f, 0.f, 0.f};
    a = __builtin_amdgcn_mfma_f32_16x16x32_bf16(qf0, kf0, a, 0, 0, 0);
    a = __builtin_amdgcn_mfma_f32_16x16x32_bf16(qf1, kf1, a, 0, 0, 0);
    sacc[jt] = a;
  }
  const float sink = sinks[h];
  const int ja = i0 - 256;
  float mx[4] = {-1e30f, -1e30f, -1e30f, -1e30f};
#pragma unroll
  for (int jt = 0; jt < 17; ++jt)
#pragma unroll
    for (int r = 0; r < 4; ++r) {
      const int qi = i0 + lg * 4 + r;
      const int jg = ja + jt * 16 + lr;
      const bool ok = (jg >= 0) && (jg <= qi) && (jg > qi - 256);
      const float sv = ok ? sacc[jt][r] * 0.125f : -1e30f;
      sacc[jt][r] = sv;
      mx[r] = fmaxf(mx[r], sv);
    }
#pragma unroll
  for (int off = 1; off < 16; off <<= 1)
#pragma unroll
    for (int r = 0; r < 4; ++r) mx[r] = fmaxf(mx[r], __shfl_xor(mx[r], off));
#pragma unroll
  for (int r = 0; r < 4; ++r) mx[r] = fmaxf(mx[r], sink);
  float sum[4] = {0.f, 0.f, 0.f, 0.f};
#pragma unroll
  for (int jt = 0; jt < 17; ++jt)
#pragma unroll
    for (int r = 0; r < 4; ++r) {
      const float e = __expf(sacc[jt][r] - mx[r]);
      sacc[jt][r] = e;
      sum[r] += e;
    }
#pragma unroll
  for (int off = 1; off < 16; off <<= 1)
#pragma unroll
    for (int r = 0; r < 4; ++r) sum[r] += __shfl_xor(sum[r], off);
  float inv[4];
#pragma unroll
  for (int r = 0; r < 4; ++r) inv[r] = 1.0f / (sum[r] + __expf(sink - mx[r]));

  __syncthreads();                 // Ks reads done -> reuse as pbuf
  u16* pb = Ks + w * 4736;         // 16 rows x stride 296
  {
    ushort4 z; z.x = 0; z.y = 0; z.z = 0; z.w = 0;
    *(ushort4*)(pb + (l >> 2) * 296 + 272 + (l & 3) * 4) = z;
  }
#pragma unroll
  for (int jt = 0; jt < 17; ++jt)
#pragma unroll
    for (int r = 0; r < 4; ++r)
      pb[(lg * 4 + r) * 296 + jt * 16 + lr] = f2b(sacc[jt][r] * inv[r]);

  f32x4 oacc[4] = {};
#pragma unroll
  for (int ks = 0; ks < 9; ++ks) {
    const bf16x8 pf = *(const bf16x8*)(pb + lr * 296 + ks * 32 + lg * 8);
#pragma unroll
    for (int dt = 0; dt < 4; ++dt) {
      int r = w * 16 + ks * 32 + lg * 8;
      r = r < 320 ? r : 0;
      const int n = r >> 6, jl = r & 63;
      const int slot = (jl >> 3) ^ (lr & 7);
      const bf16x8 vf = *(const bf16x8*)(Vs + n * 4096 + (dt * 16 + lr) * 64 + slot * 8);
      oacc[dt] = __builtin_amdgcn_mfma_f32_16x16x32_bf16(pf, vf, oacc[dt], 0, 0, 0);
    }
  }
#pragma unroll
  for (int dt = 0; dt < 4; ++dt)
#pragma unroll
    for (int r = 0; r < 4; ++r) {
      const int m = (b << 10) + i0 + lg * 4 + r;
      const int d = dt * 16 + lr;
      // 4-slot GEMM-operand swizzle within 32-col groups of row m
      const int cg = ((d >> 3) & 3) ^ (m & 3);
      ao[(m << 10) + (h << 6) + (d & ~31) + (cg << 3) + (d & 7)] = f2b(oacc[dt][r]);
    }
}

// ---------------------------------------------------------------------------
// ws layout (u16 elems):
//   q       @ 0         (4194304)   linear [B,H,N,D], LN+RoPE applied
//   k       @ 4194304   (4194304)   LN+RoPE, chunk-permuted (slot c^(pos&7))
//   vt      @ 8388608   (4194304)   transposed-chunked (written by gemm_qkv)
//   xb      @ 12582912  (4194304)   x bf16, 4-slot swizzled
//   wqkvb   @ 16777216  (3145728)   qkv_w bf16, 4-slot swizzled
//   wprojb  @ 19922944  (1048576)   proj_w bf16, 4-slot swizzled
//   ropetab @ 20971520  (262144 u16 reserved; 65536 f32 used)
//   ao      @ 21233664  (4194304)   4-slot swizzled GEMM operand
// total 50,855,936 bytes
// ---------------------------------------------------------------------------
extern "C" void kernel_launch(void* const* d_in, const int* in_sizes, int n_in,
                              void* d_out, int out_size, void* d_ws, size_t ws_size,
                              hipStream_t stream) {
  const float* x      = (const float*)d_in[0];
  const float* qkv_w  = (const float*)d_in[1];
  const float* qn_w   = (const float*)d_in[2];
  const float* qn_b   = (const float*)d_in[3];
  const float* kn_w   = (const float*)d_in[4];
  const float* kn_b   = (const float*)d_in[5];
  const float* sinks  = (const float*)d_in[6];
  const float* proj_w = (const float*)d_in[7];
  const float* proj_b = (const float*)d_in[8];
  float* out = (float*)d_out;
  u16* ws     = (u16*)d_ws;
  u16* qkv    = ws;
  u16* vtw    = ws + 8388608;
  u16* xb     = ws + 12582912;
  u16* wprojb = ws + 19922944;
  float* tab  = (float*)(ws + 20971520);
  u16* ao     = ws + 21233664;

  prep<<<4224, 256, 0, stream>>>(x, qkv_w, proj_w, xb, tab);
  gemm_qkv<<<dim3(24, 32), 256, 0, stream>>>(xb, xb + 4194304, qkv, vtw,
                                             qn_w, qn_b, kn_w, kn_b, tab, 1024);
  attn_kernel<<<1024, 256, 0, stream>>>(qkv, qkv + 4194304, vtw, sinks, ao);
  gemm_proj<<<dim3(16, 32), 256, 0, stream>>>(ao, wprojb, out, proj_b, 1024);
}

// Round 8
// 183.224 us; speedup vs baseline: 1.0960x; 1.0960x over previous
//
#include <hip/hip_runtime.h>
#include <stdint.h>

typedef unsigned short u16;
typedef __bf16 bf16x8 __attribute__((ext_vector_type(8)));
typedef float f32x4 __attribute__((ext_vector_type(4)));

__device__ __forceinline__ float b2f(u16 u) {
  union { uint32_t i; float f; } x; x.i = ((uint32_t)u) << 16; return x.f;
}
__device__ __forceinline__ u16 f2b(float f) {
  union { float f; uint32_t i; } x; x.f = f;
  uint32_t r = x.i + 0x7fffu + ((x.i >> 16) & 1u);
  return (u16)(r >> 16);
}
__device__ __forceinline__ uint4 pk8(const float4 a, const float4 b) {
  uint4 r;
  r.x = (uint32_t)f2b(a.x) | ((uint32_t)f2b(a.y) << 16);
  r.y = (uint32_t)f2b(a.z) | ((uint32_t)f2b(a.w) << 16);
  r.z = (uint32_t)f2b(b.x) | ((uint32_t)f2b(b.y) << 16);
  r.w = (uint32_t)f2b(b.z) | ((uint32_t)f2b(b.w) << 16);
  return r;
}
// async global->LDS, 16B per lane, LDS dest = wave-uniform base + lane*16
__device__ __forceinline__ void gload_lds16(const u16* g, u16* l) {
  __builtin_amdgcn_global_load_lds(
      (const __attribute__((address_space(1))) void*)g,
      (__attribute__((address_space(3))) void*)l, 16, 0, 0);
}

// ---------------------------------------------------------------------------
// prep: fp32->bf16 cvt of x|qkv_w|proj_w with 4-slot ADD GEMM-operand swizzle:
// 16B chunk c (of 4) within each 32-col group of row r -> slot (c+(r>>1))&3.
// (ADD, not XOR: quarter-wave frag reads then touch every bank exactly 2x ->
//  free 2-way aliasing, vs XOR's residual 4-way conflicts.)
// blocks 0..4095: cvt (8 elems/thread). blocks 4096..4223: RoPE table
// tab[pos*32+idx] = {cos,sin}(pos * 10000^-(idx/32)).
// ---------------------------------------------------------------------------
__launch_bounds__(256)
__global__ void prep(const float* __restrict__ x, const float* __restrict__ wq,
                     const float* __restrict__ wp, u16* __restrict__ dst,
                     float* __restrict__ tab) {
  if (blockIdx.x >= 4096) {
    const int tid = (blockIdx.x - 4096) * 256 + threadIdx.x;  // 32768
    const int pos = tid >> 5, idx = tid & 31;
    const float f = pos * exp2f(idx * -0.41524101186092029f); // -log2(1e4)/32
    float s, c;
    sincosf(f, &s, &c);
    *(float2*)(tab + tid * 2) = make_float2(c, s);
    return;
  }
  const int i = (blockIdx.x * 256 + threadIdx.x) * 8;
  const float* src; int local, base;
  if (i < 4194304)      { src = x;  local = i;           base = 0; }
  else if (i < 7340032) { src = wq; local = i - 4194304; base = 4194304; }
  else                  { src = wp; local = i - 7340032; base = 7340032; }
  const int row = local >> 10, col = local & 1023;
  const int slot = (((col >> 3) & 3) + (row >> 1)) & 3;
  const float4 a = *(const float4*)(src + local);
  const float4 b = *(const float4*)(src + local + 4);
  *(uint4*)(dst + base + (row << 10) + (col & ~31) + (slot << 3)) = pk8(a, b);
}

// ---------------------------------------------------------------------------
// QKV GEMM (lean: NO LN fusion — measured 2x that fusing LN here costs ~17us
// via VGPR/occupancy loss; the standalone ln_rope pass is ~6us).
// C[m,n] = sum_k A[m,k]*B[n,k]; operands 4-slot ADD-swizzled in global.
// 128x128 tile, BK=32 (16KB LDS), 4 waves (2x2 of 64x64), linear
// global_load_lds staging, conflict-free ADD-swizzled ds_read_b128 frags.
// Epilogue: q/k -> linear [B,H,N,D] scatter; v -> transposed-chunked
// [bh][nb][d][64] with slot (jl>>3)^(d&7) (vtrans fused).
// ---------------------------------------------------------------------------
__launch_bounds__(256)
__global__ void gemm_qkv(const u16* __restrict__ A, const u16* __restrict__ Bw,
                         u16* __restrict__ Cp, u16* __restrict__ vt, int K) {
  __shared__ __align__(16) u16 As[128 * 32];
  __shared__ __align__(16) u16 Bs[128 * 32];
  const int t = threadIdx.x;
  const int w = t >> 6, l = t & 63, lr = l & 15, lg = l >> 4;
  const int m0 = blockIdx.y * 128, n0 = blockIdx.x * 128;
  const int wm = (w >> 1) * 64, wn = (w & 1) * 64;
  const int srow = w * 32 + (l >> 2);
  const int scol = (l & 3) * 8;
  const u16* ga0 = A  + (m0 + srow) * K + scol;
  const u16* ga1 = ga0 + 16 * K;
  const u16* gb0 = Bw + (n0 + srow) * K + scol;
  const u16* gb1 = gb0 + 16 * K;
  u16* la0 = As + w * 1024;
  u16* la1 = As + w * 1024 + 512;
  u16* lb0 = Bs + w * 1024;
  u16* lb1 = Bs + w * 1024 + 512;

  f32x4 acc[4][4] = {};
  const int nk = K >> 5;
  for (int kt = 0; kt < nk; ++kt) {
    const int ko = kt * 32;
    __syncthreads();
    gload_lds16(ga0 + ko, la0);
    gload_lds16(ga1 + ko, la1);
    gload_lds16(gb0 + ko, lb0);
    gload_lds16(gb1 + ko, lb1);
    __syncthreads();
    bf16x8 af[4], bfr[4];
#pragma unroll
    for (int i = 0; i < 4; ++i) {
      const int ra = wm + i * 16 + lr;
      af[i] = *(const bf16x8*)(As + ra * 32 + (((lg + (ra >> 1)) & 3) << 3));
    }
#pragma unroll
    for (int j = 0; j < 4; ++j) {
      const int rb = wn + j * 16 + lr;
      bfr[j] = *(const bf16x8*)(Bs + rb * 32 + (((lg + (rb >> 1)) & 3) << 3));
    }
#pragma unroll
    for (int i = 0; i < 4; ++i)
#pragma unroll
      for (int j = 0; j < 4; ++j)
        acc[i][j] = __builtin_amdgcn_mfma_f32_16x16x32_bf16(af[i], bfr[j], acc[i][j], 0, 0, 0);
  }
  // epilogue. C/D layout: col=lane&15, row=(lane>>4)*4+reg
  const int whichB = blockIdx.x >> 3;              // 0=q 1=k 2=v
  const int hh = ((n0 + wn) >> 6) & 15;            // head (wave-uniform)
  if (whichB == 2) {
    // v: fused transpose into chunked [bh][nb][d][64], slot (jl>>3)^(d&7)
#pragma unroll
    for (int i = 0; i < 4; ++i)
#pragma unroll
      for (int j = 0; j < 4; ++j)
#pragma unroll
        for (int r = 0; r < 4; ++r) {
          const int gm = m0 + wm + i * 16 + lg * 4 + r;
          const int bh = (gm >> 10) * 16 + hh;
          const int pos = gm & 1023, nb = pos >> 6, jl = pos & 63;
          const int d = j * 16 + lr;
          vt[bh * 65536 + nb * 4096 + d * 64 + (((jl >> 3) ^ (d & 7)) << 3) + (jl & 7)] =
              f2b(acc[i][j][r]);
        }
    return;
  }
  u16* Cb = Cp + whichB * 4194304;
#pragma unroll
  for (int i = 0; i < 4; ++i)
#pragma unroll
    for (int j = 0; j < 4; ++j)
#pragma unroll
      for (int r = 0; r < 4; ++r) {
        const int gm = m0 + wm + i * 16 + lg * 4 + r;
        Cb[(((gm >> 10) * 16 + hh) << 16) + ((gm & 1023) << 6) + j * 16 + lr] =
            f2b(acc[i][j][r]);
      }
}

// ---------------------------------------------------------------------------
// LayerNorm(D=64) + RoPE, 8 rows/wave, 8 lanes/row, 8 elems/lane, in place.
// K region written CHUNK-PERMUTED (16B chunk c of row pos -> slot c^(pos&7))
// for attn's linear global_load_lds staging. Compact RoPE table [pos][32].
// ---------------------------------------------------------------------------
__launch_bounds__(256)
__global__ void ln_rope(u16* __restrict__ qk, const float* __restrict__ qn_w,
                        const float* __restrict__ qn_b, const float* __restrict__ kn_w,
                        const float* __restrict__ kn_b, const float* __restrict__ tab) {
  const int t = threadIdx.x, l = t & 63;
  const int wv = blockIdx.x * 4 + (t >> 6);
  const int row = wv * 8 + (l >> 3);     // 0..131071
  const int c = l & 7;
  const int which = row >> 16;           // 0 = q, 1 = k
  const int pos = row & 1023;
  const float* wgt = which ? kn_w : qn_w;
  const float* bia = which ? kn_b : qn_b;
  const u16* src = qk + row * 64 + c * 8;
  const ushort4 ra = *(const ushort4*)(src);
  const ushort4 rb = *(const ushort4*)(src + 4);
  float v[8] = {b2f(ra.x), b2f(ra.y), b2f(ra.z), b2f(ra.w),
                b2f(rb.x), b2f(rb.y), b2f(rb.z), b2f(rb.w)};
  float s = 0.f;
#pragma unroll
  for (int i = 0; i < 8; ++i) s += v[i];
#pragma unroll
  for (int off = 1; off < 8; off <<= 1) s += __shfl_xor(s, off);
  const float mu = s * 0.015625f;
  float e[8], qs = 0.f;
#pragma unroll
  for (int i = 0; i < 8; ++i) { e[i] = v[i] - mu; qs += e[i] * e[i]; }
#pragma unroll
  for (int off = 1; off < 8; off <<= 1) qs += __shfl_xor(qs, off);
  const float rstd = rsqrtf(qs * 0.015625f + 1e-5f);
  const int d0 = c * 8;
  float wb[8], bb[8];
  *(float4*)(wb) = *(const float4*)(wgt + d0);
  *(float4*)(wb + 4) = *(const float4*)(wgt + d0 + 4);
  *(float4*)(bb) = *(const float4*)(bia + d0);
  *(float4*)(bb + 4) = *(const float4*)(bia + d0 + 4);
  float n[8], r[8];
#pragma unroll
  for (int i = 0; i < 8; ++i) n[i] = e[i] * rstd * wb[i] + bb[i];
  // rotate_half partner: d^32 -> lane c^4
#pragma unroll
  for (int i = 0; i < 8; ++i) r[i] = __shfl_xor(n[i], 4);
  const bool lo = (c < 4);
#pragma unroll
  for (int i = 0; i < 8; ++i) r[i] = lo ? -r[i] : r[i];
  float cs[16];
  const int ti = (pos * 32 + (c & 3) * 8) * 2;
  *(float4*)(cs)      = *(const float4*)(tab + ti);
  *(float4*)(cs + 4)  = *(const float4*)(tab + ti + 4);
  *(float4*)(cs + 8)  = *(const float4*)(tab + ti + 8);
  *(float4*)(cs + 12) = *(const float4*)(tab + ti + 12);
  ushort4 oa, ob;
  float o[8];
#pragma unroll
  for (int i = 0; i < 8; ++i) o[i] = n[i] * cs[2 * i] + r[i] * cs[2 * i + 1];
  oa.x = f2b(o[0]); oa.y = f2b(o[1]); oa.z = f2b(o[2]); oa.w = f2b(o[3]);
  ob.x = f2b(o[4]); ob.y = f2b(o[5]); ob.z = f2b(o[6]); ob.w = f2b(o[7]);
  const int dstc = which ? (c ^ (pos & 7)) : c;   // permute K only
  u16* dst = qk + row * 64 + dstc * 8;
  *(ushort4*)(dst) = oa;
  *(ushort4*)(dst + 4) = ob;
}

// ---------------------------------------------------------------------------
// Projection GEMM: out[m,n] = sum_k ao[m,k]*wp[n,k] + bias[n], fp32 out.
// 128x64 tile (12KB LDS) -> 512 blocks = 2 blocks/CU: doubles resident
// waves to hide the K-loop barrier drains (vs 1 block/CU at 128x128).
// ADD-swizzled operands, conflict-free frag reads.
// ---------------------------------------------------------------------------
__launch_bounds__(256)
__global__ void gemm_proj(const u16* __restrict__ A, const u16* __restrict__ Bw,
                          float* __restrict__ out, const float* __restrict__ bias,
                          int K) {
  __shared__ __align__(16) u16 As[128 * 32];
  __shared__ __align__(16) u16 Bs[64 * 32];
  const int t = threadIdx.x;
  const int w = t >> 6, l = t & 63, lr = l & 15, lg = l >> 4;
  const int m0 = blockIdx.y * 128, n0 = blockIdx.x * 64;
  const int wm = (w >> 1) * 64, wn = (w & 1) * 32;
  const int srowA = w * 32 + (l >> 2);
  const int srowB = w * 16 + (l >> 2);
  const int scol = (l & 3) * 8;
  const u16* ga0 = A  + (m0 + srowA) * K + scol;
  const u16* ga1 = ga0 + 16 * K;
  const u16* gb  = Bw + (n0 + srowB) * K + scol;
  u16* la0 = As + w * 1024;
  u16* la1 = As + w * 1024 + 512;
  u16* lb  = Bs + w * 512;

  f32x4 acc[4][2] = {};
  const int nk = K >> 5;
  for (int kt = 0; kt < nk; ++kt) {
    const int ko = kt * 32;
    __syncthreads();
    gload_lds16(ga0 + ko, la0);
    gload_lds16(ga1 + ko, la1);
    gload_lds16(gb + ko, lb);
    __syncthreads();
    bf16x8 af[4], bfr[2];
#pragma unroll
    for (int i = 0; i < 4; ++i) {
      const int ra = wm + i * 16 + lr;
      af[i] = *(const bf16x8*)(As + ra * 32 + (((lg + (ra >> 1)) & 3) << 3));
    }
#pragma unroll
    for (int j = 0; j < 2; ++j) {
      const int rb = wn + j * 16 + lr;
      bfr[j] = *(const bf16x8*)(Bs + rb * 32 + (((lg + (rb >> 1)) & 3) << 3));
    }
#pragma unroll
    for (int i = 0; i < 4; ++i)
#pragma unroll
      for (int j = 0; j < 2; ++j)
        acc[i][j] = __builtin_amdgcn_mfma_f32_16x16x32_bf16(af[i], bfr[j], acc[i][j], 0, 0, 0);
  }
#pragma unroll
  for (int i = 0; i < 4; ++i)
#pragma unroll
    for (int j = 0; j < 2; ++j)
#pragma unroll
      for (int r = 0; r < 4; ++r) {
        const int gm = m0 + wm + i * 16 + lg * 4 + r;
        const int gn = n0 + wn + j * 16 + lr;
        out[(gm << 10) + gn] = acc[i][j][r] + bias[gn];
      }
}

// ---------------------------------------------------------------------------
// Sliding-window attention with sinks (LDS-staged K/V via async burst,
// swizzled sources, P-buffer aliases Ks). ao store is 4-slot ADD-swizzled
// so ao is a valid swizzled GEMM operand for the proj GEMM.
// ---------------------------------------------------------------------------
__launch_bounds__(256, 2)
__global__ void attn_kernel(const u16* __restrict__ q, const u16* __restrict__ k,
                            const u16* __restrict__ vt, const float* __restrict__ sinks,
                            u16* __restrict__ ao) {
  __shared__ __align__(16) u16 Ks[20480];   // 320 rows x 64
  __shared__ __align__(16) u16 Vs[20480];   // 5 chunks x [64][64]
  const int t = threadIdx.x, w = t >> 6, l = t & 63, lr = l & 15, lg = l >> 4;
  const int bid = blockIdx.x;
  const int qb = bid & 15, h = (bid >> 4) & 15, b = bid >> 8;
  const int i0 = qb * 64 + w * 16;
  const int bh = b * 16 + h;
  const u16* qp = q + bh * 65536;
  const u16* kp = k + bh * 65536;
  const u16* vp = vt + bh * 65536;
  const int j0 = qb * 64 - 256;

#pragma unroll
  for (int i = 0; i < 10; ++i) {
    const int c = w * 10 + i;
    int off = j0 * 64 + c * 512 + l * 8;
    off = off < 0 ? 0 : off;
    gload_lds16(kp + off, Ks + c * 512);
  }
#pragma unroll
  for (int i = 0; i < 10; ++i) {
    const int c = w * 10 + i;
    const int n = c >> 3, p = c & 7;
    int nb = qb - 4 + n;
    nb = nb < 0 ? 0 : nb;
    gload_lds16(vp + nb * 4096 + p * 512 + l * 8, Vs + c * 512);
  }
  const bf16x8 qf0 = *(const bf16x8*)(qp + (i0 + lr) * 64 + lg * 8);
  const bf16x8 qf1 = *(const bf16x8*)(qp + (i0 + lr) * 64 + 32 + lg * 8);
  __syncthreads();

  const int key = lr & 7;
  f32x4 sacc[17];
#pragma unroll
  for (int jt = 0; jt < 17; ++jt) {
    const int r = w * 16 + jt * 16 + lr;
    const bf16x8 kf0 = *(const bf16x8*)(Ks + r * 64 + ((lg ^ key)) * 8);
    const bf16x8 kf1 = *(const bf16x8*)(Ks + r * 64 + (((lg + 4) ^ key)) * 8);
    f32x4 a = {0.f, 0.f, 0.f, 0.f};
    a = __builtin_amdgcn_mfma_f32_16x16x32_bf16(qf0, kf0, a, 0, 0, 0);
    a = __builtin_amdgcn_mfma_f32_16x16x32_bf16(qf1, kf1, a, 0, 0, 0);
    sacc[jt] = a;
  }
  const float sink = sinks[h];
  const int ja = i0 - 256;
  float mx[4] = {-1e30f, -1e30f, -1e30f, -1e30f};
#pragma unroll
  for (int jt = 0; jt < 17; ++jt)
#pragma unroll
    for (int r = 0; r < 4; ++r) {
      const int qi = i0 + lg * 4 + r;
      const int jg = ja + jt * 16 + lr;
      const bool ok = (jg >= 0) && (jg <= qi) && (jg > qi - 256);
      const float sv = ok ? sacc[jt][r] * 0.125f : -1e30f;
      sacc[jt][r] = sv;
      mx[r] = fmaxf(mx[r], sv);
    }
#pragma unroll
  for (int off = 1; off < 16; off <<= 1)
#pragma unroll
    for (int r = 0; r < 4; ++r) mx[r] = fmaxf(mx[r], __shfl_xor(mx[r], off));
#pragma unroll
  for (int r = 0; r < 4; ++r) mx[r] = fmaxf(mx[r], sink);
  float sum[4] = {0.f, 0.f, 0.f, 0.f};
#pragma unroll
  for (int jt = 0; jt < 17; ++jt)
#pragma unroll
    for (int r = 0; r < 4; ++r) {
      const float e = __expf(sacc[jt][r] - mx[r]);
      sacc[jt][r] = e;
      sum[r] += e;
    }
#pragma unroll
  for (int off = 1; off < 16; off <<= 1)
#pragma unroll
    for (int r = 0; r < 4; ++r) sum[r] += __shfl_xor(sum[r], off);
  float inv[4];
#pragma unroll
  for (int r = 0; r < 4; ++r) inv[r] = 1.0f / (sum[r] + __expf(sink - mx[r]));

  __syncthreads();                 // Ks reads done -> reuse as pbuf
  u16* pb = Ks + w * 4736;         // 16 rows x stride 296
  {
    ushort4 z; z.x = 0; z.y = 0; z.z = 0; z.w = 0;
    *(ushort4*)(pb + (l >> 2) * 296 + 272 + (l & 3) * 4) = z;
  }
#pragma unroll
  for (int jt = 0; jt < 17; ++jt)
#pragma unroll
    for (int r = 0; r < 4; ++r)
      pb[(lg * 4 + r) * 296 + jt * 16 + lr] = f2b(sacc[jt][r] * inv[r]);

  f32x4 oacc[4] = {};
#pragma unroll
  for (int ks = 0; ks < 9; ++ks) {
    const bf16x8 pf = *(const bf16x8*)(pb + lr * 296 + ks * 32 + lg * 8);
#pragma unroll
    for (int dt = 0; dt < 4; ++dt) {
      int r = w * 16 + ks * 32 + lg * 8;
      r = r < 320 ? r : 0;
      const int n = r >> 6, jl = r & 63;
      const int slot = (jl >> 3) ^ (lr & 7);
      const bf16x8 vf = *(const bf16x8*)(Vs + n * 4096 + (dt * 16 + lr) * 64 + slot * 8);
      oacc[dt] = __builtin_amdgcn_mfma_f32_16x16x32_bf16(pf, vf, oacc[dt], 0, 0, 0);
    }
  }
#pragma unroll
  for (int dt = 0; dt < 4; ++dt)
#pragma unroll
    for (int r = 0; r < 4; ++r) {
      const int m = (b << 10) + i0 + lg * 4 + r;
      const int d = dt * 16 + lr;
      // 4-slot ADD GEMM-operand swizzle within 32-col groups of row m
      const int cg = (((d >> 3) & 3) + (m >> 1)) & 3;
      ao[(m << 10) + (h << 6) + (d & ~31) + (cg << 3) + (d & 7)] = f2b(oacc[dt][r]);
    }
}

// ---------------------------------------------------------------------------
// ws layout (u16 elems):
//   q       @ 0         (4194304)   linear [B,H,N,D] (ln_rope applies LN+RoPE)
//   k       @ 4194304   (4194304)   LN+RoPE, chunk-permuted (slot c^(pos&7))
//   vt      @ 8388608   (4194304)   transposed-chunked (written by gemm_qkv)
//   xb      @ 12582912  (4194304)   x bf16, 4-slot ADD-swizzled
//   wqkvb   @ 16777216  (3145728)   qkv_w bf16, ADD-swizzled
//   wprojb  @ 19922944  (1048576)   proj_w bf16, ADD-swizzled
//   ropetab @ 20971520  (262144 u16 reserved; 65536 f32 used)
//   ao      @ 21233664  (4194304)   ADD-swizzled GEMM operand
// total 50,855,936 bytes
// ---------------------------------------------------------------------------
extern "C" void kernel_launch(void* const* d_in, const int* in_sizes, int n_in,
                              void* d_out, int out_size, void* d_ws, size_t ws_size,
                              hipStream_t stream) {
  const float* x      = (const float*)d_in[0];
  const float* qkv_w  = (const float*)d_in[1];
  const float* qn_w   = (const float*)d_in[2];
  const float* qn_b   = (const float*)d_in[3];
  const float* kn_w   = (const float*)d_in[4];
  const float* kn_b   = (const float*)d_in[5];
  const float* sinks  = (const float*)d_in[6];
  const float* proj_w = (const float*)d_in[7];
  const float* proj_b = (const float*)d_in[8];
  float* out = (float*)d_out;
  u16* ws     = (u16*)d_ws;
  u16* qkv    = ws;
  u16* vtw    = ws + 8388608;
  u16* xb     = ws + 12582912;
  u16* wprojb = ws + 19922944;
  float* tab  = (float*)(ws + 20971520);
  u16* ao     = ws + 21233664;

  prep<<<4224, 256, 0, stream>>>(x, qkv_w, proj_w, xb, tab);
  gemm_qkv<<<dim3(24, 32), 256, 0, stream>>>(xb, xb + 4194304, qkv, vtw, 1024);
  ln_rope<<<4096, 256, 0, stream>>>(qkv, qn_w, qn_b, kn_w, kn_b, tab);
  attn_kernel<<<1024, 256, 0, stream>>>(qkv, qkv + 4194304, vtw, sinks, ao);
  gemm_proj<<<dim3(16, 32), 256, 0, stream>>>(ao, wprojb, out, proj_b, 1024);
}

// Round 9
// 173.427 us; speedup vs baseline: 1.1579x; 1.0565x over previous
//
#include <hip/hip_runtime.h>
#include <stdint.h>

typedef unsigned short u16;
typedef __bf16 bf16x8 __attribute__((ext_vector_type(8)));
typedef float f32x4 __attribute__((ext_vector_type(4)));

__device__ __forceinline__ float b2f(u16 u) {
  union { uint32_t i; float f; } x; x.i = ((uint32_t)u) << 16; return x.f;
}
__device__ __forceinline__ u16 f2b(float f) {
  union { float f; uint32_t i; } x; x.f = f;
  uint32_t r = x.i + 0x7fffu + ((x.i >> 16) & 1u);
  return (u16)(r >> 16);
}
__device__ __forceinline__ uint4 pk8(const float4 a, const float4 b) {
  uint4 r;
  r.x = (uint32_t)f2b(a.x) | ((uint32_t)f2b(a.y) << 16);
  r.y = (uint32_t)f2b(a.z) | ((uint32_t)f2b(a.w) << 16);
  r.z = (uint32_t)f2b(b.x) | ((uint32_t)f2b(b.y) << 16);
  r.w = (uint32_t)f2b(b.z) | ((uint32_t)f2b(b.w) << 16);
  return r;
}
// async global->LDS, 16B per lane, LDS dest = wave-uniform base + lane*16
__device__ __forceinline__ void gload_lds16(const u16* g, u16* l) {
  __builtin_amdgcn_global_load_lds(
      (const __attribute__((address_space(1))) void*)g,
      (__attribute__((address_space(3))) void*)l, 16, 0, 0);
}

// ---------------------------------------------------------------------------
// prep: fp32->bf16 cvt of x|qkv_w|proj_w with 8-slot XOR GEMM-operand swizzle
// (r5-measured 0 LDS conflicts): 16B chunk c (of 8) within each 64-col group
// of row r -> slot c^(r&7).
// blocks 0..4095: cvt (8 elems/thread). blocks 4096..4223: RoPE table
// tab[pos*32+idx] = {cos,sin}(pos * 10000^-(idx/32)).
// ---------------------------------------------------------------------------
__launch_bounds__(256)
__global__ void prep(const float* __restrict__ x, const float* __restrict__ wq,
                     const float* __restrict__ wp, u16* __restrict__ dst,
                     float* __restrict__ tab) {
  if (blockIdx.x >= 4096) {
    const int tid = (blockIdx.x - 4096) * 256 + threadIdx.x;  // 32768
    const int pos = tid >> 5, idx = tid & 31;
    const float f = pos * exp2f(idx * -0.41524101186092029f); // -log2(1e4)/32
    float s, c;
    sincosf(f, &s, &c);
    *(float2*)(tab + tid * 2) = make_float2(c, s);
    return;
  }
  const int i = (blockIdx.x * 256 + threadIdx.x) * 8;
  const float* src; int local, base;
  if (i < 4194304)      { src = x;  local = i;           base = 0; }
  else if (i < 7340032) { src = wq; local = i - 4194304; base = 4194304; }
  else                  { src = wp; local = i - 7340032; base = 7340032; }
  const int row = local >> 10, col = local & 1023;
  const int slot = ((col >> 3) & 7) ^ (row & 7);
  const float4 a = *(const float4*)(src + local);
  const float4 b = *(const float4*)(src + local + 4);
  *(uint4*)(dst + base + (row << 10) + (col & ~63) + (slot << 3)) = pk8(a, b);
}

// ---------------------------------------------------------------------------
// QKV GEMM, lean (no LN fusion — measured twice: fusing LN here costs ~29us
// via VGPR/occupancy loss). C[m,n] = sum_k A[m,k]*B[n,k]; operands 8-slot
// XOR-swizzled in global. 128x128 tile, BK=64 (32KB LDS, 16 iters = half the
// barrier drains of BK=32), 4 waves (2x2 of 64x64), linear global_load_lds
// staging (8x 1KB insts/wave/iter), conflict-free swizzled ds_read_b128.
// Epilogue: q/k -> linear [B,H,N,D] scatter; v -> transposed-chunked
// [bh][nb][d][64] with slot (jl>>3)^(d&7) (vtrans fused).
// ---------------------------------------------------------------------------
__launch_bounds__(256)
__global__ void gemm_qkv(const u16* __restrict__ A, const u16* __restrict__ Bw,
                         u16* __restrict__ Cp, u16* __restrict__ vt, int K) {
  __shared__ __align__(16) u16 As[128 * 64];
  __shared__ __align__(16) u16 Bs[128 * 64];
  const int t = threadIdx.x;
  const int w = t >> 6, l = t & 63, lr = l & 15, lg = l >> 4;
  const int m0 = blockIdx.y * 128, n0 = blockIdx.x * 128;
  const int wm = (w >> 1) * 64, wn = (w & 1) * 64;
  // staging: wave w rows [w*32, w*32+32); inst i covers 8 rows x 64 cols
  const int srow = w * 32 + (l >> 3);
  const int scol = (l & 7) * 8;
  const u16* gA = A  + (m0 + srow) * K + scol;
  const u16* gB = Bw + (n0 + srow) * K + scol;

  f32x4 acc[4][4] = {};
  const int nk = K >> 6;
  for (int kt = 0; kt < nk; ++kt) {
    const int ko = kt * 64;
    __syncthreads();
#pragma unroll
    for (int i = 0; i < 4; ++i)
      gload_lds16(gA + i * 8 * K + ko, As + (w * 32 + i * 8) * 64);
#pragma unroll
    for (int i = 0; i < 4; ++i)
      gload_lds16(gB + i * 8 * K + ko, Bs + (w * 32 + i * 8) * 64);
    __syncthreads();
    bf16x8 af0[4], af1[4], bf0[4], bf1[4];
#pragma unroll
    for (int i = 0; i < 4; ++i) {
      const int ra = wm + i * 16 + lr;
      const int sa = (lg ^ (ra & 7)) * 8;
      af0[i] = *(const bf16x8*)(As + ra * 64 + sa);
      af1[i] = *(const bf16x8*)(As + ra * 64 + (sa ^ 32));
    }
#pragma unroll
    for (int j = 0; j < 4; ++j) {
      const int rb = wn + j * 16 + lr;
      const int sb = (lg ^ (rb & 7)) * 8;
      bf0[j] = *(const bf16x8*)(Bs + rb * 64 + sb);
      bf1[j] = *(const bf16x8*)(Bs + rb * 64 + (sb ^ 32));
    }
#pragma unroll
    for (int i = 0; i < 4; ++i)
#pragma unroll
      for (int j = 0; j < 4; ++j) {
        acc[i][j] = __builtin_amdgcn_mfma_f32_16x16x32_bf16(af0[i], bf0[j], acc[i][j], 0, 0, 0);
        acc[i][j] = __builtin_amdgcn_mfma_f32_16x16x32_bf16(af1[i], bf1[j], acc[i][j], 0, 0, 0);
      }
  }
  // epilogue. C/D layout: col=lane&15, row=(lane>>4)*4+reg
  const int whichB = blockIdx.x >> 3;              // 0=q 1=k 2=v
  const int hh = ((n0 + wn) >> 6) & 15;            // head (wave-uniform)
  if (whichB == 2) {
    // v: fused transpose into chunked [bh][nb][d][64], slot (jl>>3)^(d&7)
#pragma unroll
    for (int i = 0; i < 4; ++i)
#pragma unroll
      for (int j = 0; j < 4; ++j)
#pragma unroll
        for (int r = 0; r < 4; ++r) {
          const int gm = m0 + wm + i * 16 + lg * 4 + r;
          const int bh = (gm >> 10) * 16 + hh;
          const int pos = gm & 1023, nb = pos >> 6, jl = pos & 63;
          const int d = j * 16 + lr;
          vt[bh * 65536 + nb * 4096 + d * 64 + (((jl >> 3) ^ (d & 7)) << 3) + (jl & 7)] =
              f2b(acc[i][j][r]);
        }
    return;
  }
  u16* Cb = Cp + whichB * 4194304;
#pragma unroll
  for (int i = 0; i < 4; ++i)
#pragma unroll
    for (int j = 0; j < 4; ++j)
#pragma unroll
      for (int r = 0; r < 4; ++r) {
        const int gm = m0 + wm + i * 16 + lg * 4 + r;
        Cb[(((gm >> 10) * 16 + hh) << 16) + ((gm & 1023) << 6) + j * 16 + lr] =
            f2b(acc[i][j][r]);
      }
}

// ---------------------------------------------------------------------------
// LayerNorm(D=64) + RoPE, 8 rows/wave, 8 lanes/row, 8 elems/lane, in place.
// K region written CHUNK-PERMUTED (16B chunk c of row pos -> slot c^(pos&7))
// for attn's linear global_load_lds staging. Compact RoPE table [pos][32].
// ---------------------------------------------------------------------------
__launch_bounds__(256)
__global__ void ln_rope(u16* __restrict__ qk, const float* __restrict__ qn_w,
                        const float* __restrict__ qn_b, const float* __restrict__ kn_w,
                        const float* __restrict__ kn_b, const float* __restrict__ tab) {
  const int t = threadIdx.x, l = t & 63;
  const int wv = blockIdx.x * 4 + (t >> 6);
  const int row = wv * 8 + (l >> 3);     // 0..131071
  const int c = l & 7;
  const int which = row >> 16;           // 0 = q, 1 = k
  const int pos = row & 1023;
  const float* wgt = which ? kn_w : qn_w;
  const float* bia = which ? kn_b : qn_b;
  const u16* src = qk + row * 64 + c * 8;
  const ushort4 ra = *(const ushort4*)(src);
  const ushort4 rb = *(const ushort4*)(src + 4);
  float v[8] = {b2f(ra.x), b2f(ra.y), b2f(ra.z), b2f(ra.w),
                b2f(rb.x), b2f(rb.y), b2f(rb.z), b2f(rb.w)};
  float s = 0.f;
#pragma unroll
  for (int i = 0; i < 8; ++i) s += v[i];
#pragma unroll
  for (int off = 1; off < 8; off <<= 1) s += __shfl_xor(s, off);
  const float mu = s * 0.015625f;
  float e[8], qs = 0.f;
#pragma unroll
  for (int i = 0; i < 8; ++i) { e[i] = v[i] - mu; qs += e[i] * e[i]; }
#pragma unroll
  for (int off = 1; off < 8; off <<= 1) qs += __shfl_xor(qs, off);
  const float rstd = rsqrtf(qs * 0.015625f + 1e-5f);
  const int d0 = c * 8;
  float wb[8], bb[8];
  *(float4*)(wb) = *(const float4*)(wgt + d0);
  *(float4*)(wb + 4) = *(const float4*)(wgt + d0 + 4);
  *(float4*)(bb) = *(const float4*)(bia + d0);
  *(float4*)(bb + 4) = *(const float4*)(bia + d0 + 4);
  float n[8], r[8];
#pragma unroll
  for (int i = 0; i < 8; ++i) n[i] = e[i] * rstd * wb[i] + bb[i];
  // rotate_half partner: d^32 -> lane c^4
#pragma unroll
  for (int i = 0; i < 8; ++i) r[i] = __shfl_xor(n[i], 4);
  const bool lo = (c < 4);
#pragma unroll
  for (int i = 0; i < 8; ++i) r[i] = lo ? -r[i] : r[i];
  float cs[16];
  const int ti = (pos * 32 + (c & 3) * 8) * 2;
  *(float4*)(cs)      = *(const float4*)(tab + ti);
  *(float4*)(cs + 4)  = *(const float4*)(tab + ti + 4);
  *(float4*)(cs + 8)  = *(const float4*)(tab + ti + 8);
  *(float4*)(cs + 12) = *(const float4*)(tab + ti + 12);
  ushort4 oa, ob;
  float o[8];
#pragma unroll
  for (int i = 0; i < 8; ++i) o[i] = n[i] * cs[2 * i] + r[i] * cs[2 * i + 1];
  oa.x = f2b(o[0]); oa.y = f2b(o[1]); oa.z = f2b(o[2]); oa.w = f2b(o[3]);
  ob.x = f2b(o[4]); ob.y = f2b(o[5]); ob.z = f2b(o[6]); ob.w = f2b(o[7]);
  const int dstc = which ? (c ^ (pos & 7)) : c;   // permute K only
  u16* dst = qk + row * 64 + dstc * 8;
  *(ushort4*)(dst) = oa;
  *(ushort4*)(dst + 4) = ob;
}

// ---------------------------------------------------------------------------
// Projection GEMM: out[m,n] = sum_k ao[m,k]*wp[n,k] + bias[n], fp32 out.
// 128x64 tile, BK=64 (24KB LDS) -> 512 blocks = 2 blocks/CU. 8-slot
// XOR-swizzled operands, conflict-free frag reads, 16 K-iters.
// ---------------------------------------------------------------------------
__launch_bounds__(256)
__global__ void gemm_proj(const u16* __restrict__ A, const u16* __restrict__ Bw,
                          float* __restrict__ out, const float* __restrict__ bias,
                          int K) {
  __shared__ __align__(16) u16 As[128 * 64];
  __shared__ __align__(16) u16 Bs[64 * 64];
  const int t = threadIdx.x;
  const int w = t >> 6, l = t & 63, lr = l & 15, lg = l >> 4;
  const int m0 = blockIdx.y * 128, n0 = blockIdx.x * 64;
  const int wm = (w >> 1) * 64, wn = (w & 1) * 32;
  const int srowA = w * 32 + (l >> 3);
  const int srowB = w * 16 + (l >> 3);
  const int scol = (l & 7) * 8;
  const u16* gA = A  + (m0 + srowA) * K + scol;
  const u16* gB = Bw + (n0 + srowB) * K + scol;

  f32x4 acc[4][2] = {};
  const int nk = K >> 6;
  for (int kt = 0; kt < nk; ++kt) {
    const int ko = kt * 64;
    __syncthreads();
#pragma unroll
    for (int i = 0; i < 4; ++i)
      gload_lds16(gA + i * 8 * K + ko, As + (w * 32 + i * 8) * 64);
#pragma unroll
    for (int i = 0; i < 2; ++i)
      gload_lds16(gB + i * 8 * K + ko, Bs + (w * 16 + i * 8) * 64);
    __syncthreads();
    bf16x8 af0[4], af1[4], bf0[2], bf1[2];
#pragma unroll
    for (int i = 0; i < 4; ++i) {
      const int ra = wm + i * 16 + lr;
      const int sa = (lg ^ (ra & 7)) * 8;
      af0[i] = *(const bf16x8*)(As + ra * 64 + sa);
      af1[i] = *(const bf16x8*)(As + ra * 64 + (sa ^ 32));
    }
#pragma unroll
    for (int j = 0; j < 2; ++j) {
      const int rb = wn + j * 16 + lr;
      const int sb = (lg ^ (rb & 7)) * 8;
      bf0[j] = *(const bf16x8*)(Bs + rb * 64 + sb);
      bf1[j] = *(const bf16x8*)(Bs + rb * 64 + (sb ^ 32));
    }
#pragma unroll
    for (int i = 0; i < 4; ++i)
#pragma unroll
      for (int j = 0; j < 2; ++j) {
        acc[i][j] = __builtin_amdgcn_mfma_f32_16x16x32_bf16(af0[i], bf0[j], acc[i][j], 0, 0, 0);
        acc[i][j] = __builtin_amdgcn_mfma_f32_16x16x32_bf16(af1[i], bf1[j], acc[i][j], 0, 0, 0);
      }
  }
#pragma unroll
  for (int i = 0; i < 4; ++i)
#pragma unroll
    for (int j = 0; j < 2; ++j)
#pragma unroll
      for (int r = 0; r < 4; ++r) {
        const int gm = m0 + wm + i * 16 + lg * 4 + r;
        const int gn = n0 + wn + j * 16 + lr;
        out[(gm << 10) + gn] = acc[i][j][r] + bias[gn];
      }
}

// ---------------------------------------------------------------------------
// Sliding-window attention with sinks (LDS-staged K/V via async burst,
// swizzled sources, P-buffer aliases Ks). ao store is 8-slot XOR-swizzled
// (chunk (d>>3) of the 64-col head group -> slot (d>>3)^(m&7)) so ao is a
// valid swizzled GEMM operand for the proj GEMM.
// ---------------------------------------------------------------------------
__launch_bounds__(256, 2)
__global__ void attn_kernel(const u16* __restrict__ q, const u16* __restrict__ k,
                            const u16* __restrict__ vt, const float* __restrict__ sinks,
                            u16* __restrict__ ao) {
  __shared__ __align__(16) u16 Ks[20480];   // 320 rows x 64
  __shared__ __align__(16) u16 Vs[20480];   // 5 chunks x [64][64]
  const int t = threadIdx.x, w = t >> 6, l = t & 63, lr = l & 15, lg = l >> 4;
  const int bid = blockIdx.x;
  const int qb = bid & 15, h = (bid >> 4) & 15, b = bid >> 8;
  const int i0 = qb * 64 + w * 16;
  const int bh = b * 16 + h;
  const u16* qp = q + bh * 65536;
  const u16* kp = k + bh * 65536;
  const u16* vp = vt + bh * 65536;
  const int j0 = qb * 64 - 256;

#pragma unroll
  for (int i = 0; i < 10; ++i) {
    const int c = w * 10 + i;
    int off = j0 * 64 + c * 512 + l * 8;
    off = off < 0 ? 0 : off;
    gload_lds16(kp + off, Ks + c * 512);
  }
#pragma unroll
  for (int i = 0; i < 10; ++i) {
    const int c = w * 10 + i;
    const int n = c >> 3, p = c & 7;
    int nb = qb - 4 + n;
    nb = nb < 0 ? 0 : nb;
    gload_lds16(vp + nb * 4096 + p * 512 + l * 8, Vs + c * 512);
  }
  const bf16x8 qf0 = *(const bf16x8*)(qp + (i0 + lr) * 64 + lg * 8);
  const bf16x8 qf1 = *(const bf16x8*)(qp + (i0 + lr) * 64 + 32 + lg * 8);
  __syncthreads();

  const int key = lr & 7;
  f32x4 sacc[17];
#pragma unroll
  for (int jt = 0; jt < 17; ++jt) {
    const int r = w * 16 + jt * 16 + lr;
    const bf16x8 kf0 = *(const bf16x8*)(Ks + r * 64 + ((lg ^ key)) * 8);
    const bf16x8 kf1 = *(const bf16x8*)(Ks + r * 64 + (((lg + 4) ^ key)) * 8);
    f32x4 a = {0.f, 0.f, 0.f, 0.f};
    a = __builtin_amdgcn_mfma_f32_16x16x32_bf16(qf0, kf0, a, 0, 0, 0);
    a = __builtin_amdgcn_mfma_f32_16x16x32_bf16(qf1, kf1, a, 0, 0, 0);
    sacc[jt] = a;
  }
  const float sink = sinks[h];
  const int ja = i0 - 256;
  float mx[4] = {-1e30f, -1e30f, -1e30f, -1e30f};
#pragma unroll
  for (int jt = 0; jt < 17; ++jt)
#pragma unroll
    for (int r = 0; r < 4; ++r) {
      const int qi = i0 + lg * 4 + r;
      const int jg = ja + jt * 16 + lr;
      const bool ok = (jg >= 0) && (jg <= qi) && (jg > qi - 256);
      const float sv = ok ? sacc[jt][r] * 0.125f : -1e30f;
      sacc[jt][r] = sv;
      mx[r] = fmaxf(mx[r], sv);
    }
#pragma unroll
  for (int off = 1; off < 16; off <<= 1)
#pragma unroll
    for (int r = 0; r < 4; ++r) mx[r] = fmaxf(mx[r], __shfl_xor(mx[r], off));
#pragma unroll
  for (int r = 0; r < 4; ++r) mx[r] = fmaxf(mx[r], sink);
  float sum[4] = {0.f, 0.f, 0.f, 0.f};
#pragma unroll
  for (int jt = 0; jt < 17; ++jt)
#pragma unroll
    for (int r = 0; r < 4; ++r) {
      const float e = __expf(sacc[jt][r] - mx[r]);
      sacc[jt][r] = e;
      sum[r] += e;
    }
#pragma unroll
  for (int off = 1; off < 16; off <<= 1)
#pragma unroll
    for (int r = 0; r < 4; ++r) sum[r] += __shfl_xor(sum[r], off);
  float inv[4];
#pragma unroll
  for (int r = 0; r < 4; ++r) inv[r] = 1.0f / (sum[r] + __expf(sink - mx[r]));

  __syncthreads();                 // Ks reads done -> reuse as pbuf
  u16* pb = Ks + w * 4736;         // 16 rows x stride 296
  {
    ushort4 z; z.x = 0; z.y = 0; z.z = 0; z.w = 0;
    *(ushort4*)(pb + (l >> 2) * 296 + 272 + (l & 3) * 4) = z;
  }
#pragma unroll
  for (int jt = 0; jt < 17; ++jt)
#pragma unroll
    for (int r = 0; r < 4; ++r)
      pb[(lg * 4 + r) * 296 + jt * 16 + lr] = f2b(sacc[jt][r] * inv[r]);

  f32x4 oacc[4] = {};
#pragma unroll
  for (int ks = 0; ks < 9; ++ks) {
    const bf16x8 pf = *(const bf16x8*)(pb + lr * 296 + ks * 32 + lg * 8);
#pragma unroll
    for (int dt = 0; dt < 4; ++dt) {
      int r = w * 16 + ks * 32 + lg * 8;
      r = r < 320 ? r : 0;
      const int n = r >> 6, jl = r & 63;
      const int slot = (jl >> 3) ^ (lr & 7);
      const bf16x8 vf = *(const bf16x8*)(Vs + n * 4096 + (dt * 16 + lr) * 64 + slot * 8);
      oacc[dt] = __builtin_amdgcn_mfma_f32_16x16x32_bf16(pf, vf, oacc[dt], 0, 0, 0);
    }
  }
#pragma unroll
  for (int dt = 0; dt < 4; ++dt)
#pragma unroll
    for (int r = 0; r < 4; ++r) {
      const int m = (b << 10) + i0 + lg * 4 + r;
      // 8-slot XOR GEMM-operand swizzle within the 64-col head group
      const int cg = (dt * 2 + (lr >> 3)) ^ (m & 7);
      ao[(m << 10) + (h << 6) + (cg << 3) + (lr & 7)] = f2b(oacc[dt][r]);
    }
}

// ---------------------------------------------------------------------------
// ws layout (u16 elems):
//   q       @ 0         (4194304)   linear [B,H,N,D] (ln_rope applies LN+RoPE)
//   k       @ 4194304   (4194304)   LN+RoPE, chunk-permuted (slot c^(pos&7))
//   vt      @ 8388608   (4194304)   transposed-chunked (written by gemm_qkv)
//   xb      @ 12582912  (4194304)   x bf16, 8-slot XOR-swizzled
//   wqkvb   @ 16777216  (3145728)   qkv_w bf16, XOR-swizzled
//   wprojb  @ 19922944  (1048576)   proj_w bf16, XOR-swizzled
//   ropetab @ 20971520  (262144 u16 reserved; 65536 f32 used)
//   ao      @ 21233664  (4194304)   XOR-swizzled GEMM operand
// total 50,855,936 bytes
// ---------------------------------------------------------------------------
extern "C" void kernel_launch(void* const* d_in, const int* in_sizes, int n_in,
                              void* d_out, int out_size, void* d_ws, size_t ws_size,
                              hipStream_t stream) {
  const float* x      = (const float*)d_in[0];
  const float* qkv_w  = (const float*)d_in[1];
  const float* qn_w   = (const float*)d_in[2];
  const float* qn_b   = (const float*)d_in[3];
  const float* kn_w   = (const float*)d_in[4];
  const float* kn_b   = (const float*)d_in[5];
  const float* sinks  = (const float*)d_in[6];
  const float* proj_w = (const float*)d_in[7];
  const float* proj_b = (const float*)d_in[8];
  float* out = (float*)d_out;
  u16* ws     = (u16*)d_ws;
  u16* qkv    = ws;
  u16* vtw    = ws + 8388608;
  u16* xb     = ws + 12582912;
  u16* wprojb = ws + 19922944;
  float* tab  = (float*)(ws + 20971520);
  u16* ao     = ws + 21233664;

  prep<<<4224, 256, 0, stream>>>(x, qkv_w, proj_w, xb, tab);
  gemm_qkv<<<dim3(24, 32), 256, 0, stream>>>(xb, xb + 4194304, qkv, vtw, 1024);
  ln_rope<<<4096, 256, 0, stream>>>(qkv, qn_w, qn_b, kn_w, kn_b, tab);
  attn_kernel<<<1024, 256, 0, stream>>>(qkv, qkv + 4194304, vtw, sinks, ao);
  gemm_proj<<<dim3(16, 32), 256, 0, stream>>>(ao, wprojb, out, proj_b, 1024);
}